// Round 1
// baseline (1366.333 us; speedup 1.0000x reference)
//
#include <hip/hip_runtime.h>
#include <math.h>

#define C_IN 256
#define H_   64
#define W_   64
#define B_   8
#define COUT 256
#define HW   (H_*W_)
#define CKTOT (C_IN*9)      // 2304

// ---------------------------------------------------------------------------
// Kernel A: offset-predicting conv (3x3, pad 1).  Grid (128, 8):
//   blockIdx.x*256+tid -> pixel (b,h,w); blockIdx.y -> channel split s (32 c each)
//   writes partial sums to parts[s][ (b*18+o)*HW + h*W + w ]
// ---------------------------------------------------------------------------
__global__ __launch_bounds__(256) void offset_conv_kernel(
    const float* __restrict__ x, const float* __restrict__ ow,
    float* __restrict__ parts)
{
    int p = blockIdx.x * 256 + threadIdx.x;      // 0..32767
    int b = p >> 12;
    int h = (p >> 6) & 63;
    int w = p & 63;
    int c0 = blockIdx.y * 32;

    int   idx[9];
    float msk[9];
#pragma unroll
    for (int k = 0; k < 9; ++k) {
        int yy = h + (k / 3) - 1, xx = w + (k % 3) - 1;
        bool v = (yy >= 0) & (yy < H_) & (xx >= 0) & (xx < W_);
        int yc = min(max(yy, 0), H_ - 1), xc = min(max(xx, 0), W_ - 1);
        idx[k] = yc * W_ + xc;
        msk[k] = v ? 1.f : 0.f;
    }

    float acc[18];
#pragma unroll
    for (int o = 0; o < 18; ++o) acc[o] = 0.f;

    const float* xb = x + (size_t)b * C_IN * HW;
    for (int c = c0; c < c0 + 32; ++c) {
        float xn[9];
#pragma unroll
        for (int k = 0; k < 9; ++k) xn[k] = msk[k] * xb[(size_t)c * HW + idx[k]];
#pragma unroll
        for (int o = 0; o < 18; ++o) {
#pragma unroll
            for (int k = 0; k < 9; ++k)
                acc[o] += xn[k] * ow[(o * C_IN + c) * 9 + k];
        }
    }

    float* outp = parts + (size_t)blockIdx.y * (18 * B_ * HW);
#pragma unroll
    for (int o = 0; o < 18; ++o)
        outp[((size_t)b * 18 + o) * HW + h * W_ + w] = acc[o];
}

// ---------------------------------------------------------------------------
// Kernel R: reduce the 8 offset partials.  Grid 576 x 256, float4 per thread.
// ---------------------------------------------------------------------------
__global__ __launch_bounds__(256) void offset_reduce_kernel(
    const float* __restrict__ parts, float* __restrict__ offs)
{
    int i = blockIdx.x * 256 + threadIdx.x;      // float4 index, 0..147455
    const int n = 18 * B_ * HW;                  // 589824 floats per partial
    float4 a = ((const float4*)parts)[i];
#pragma unroll
    for (int s = 1; s < 8; ++s) {
        float4 b = ((const float4*)(parts + (size_t)s * n))[i];
        a.x += b.x; a.y += b.y; a.z += b.z; a.w += b.w;
    }
    ((float4*)offs)[i] = a;
}

// ---------------------------------------------------------------------------
// Kernel T: transpose deform_w [256][2304] -> wT [2304][256]
// ---------------------------------------------------------------------------
__global__ __launch_bounds__(256) void transpose_w_kernel(
    const float* __restrict__ dw, float* __restrict__ wT)
{
    int ck = blockIdx.x;        // 0..2303
    int o  = threadIdx.x;       // 0..255
    wT[(size_t)ck * COUT + o] = dw[(size_t)o * CKTOT + ck];
}

__device__ __forceinline__ void fma4(float4& a, float w, const float4& p)
{
    a.x += w * p.x; a.y += w * p.y; a.z += w * p.z; a.w += w * p.w;
}

// ---------------------------------------------------------------------------
// Kernel B: deformable conv. One block per (b, ho) row (512 blocks, 256 thr).
//   phase 0: bilinear metadata (idx4 + w4 per (px,k)) into LDS
//   loop 32 chunks of 8 channels: gather patches into LDS, register-tile GEMM
//   epilogue: write y, shuffle-reduce per-(b,o) sum/sumsq -> atomics
// ---------------------------------------------------------------------------
__global__ __launch_bounds__(256, 2) void deform_gemm_kernel(
    const float* __restrict__ x, const float* __restrict__ offs,
    const float* __restrict__ wT, float* __restrict__ y,
    float* __restrict__ sum_, float* __restrict__ sumsq_)
{
    __shared__ int4   meta_i[576];                 // [k][px]
    __shared__ float4 meta_w[576];
    __shared__ __align__(16) float p_lds[72 * 64]; // [ck][px]

    const int tid = threadIdx.x;
    const int blk = blockIdx.x;        // b*64 + ho
    const int b   = blk >> 6;
    const int ho  = blk & 63;

    // ---- phase 0: sampling metadata for 64 px x 9 taps ----
    for (int e = tid; e < 576; e += 256) {
        int kk = e >> 6;               // tap 0..8
        int px = e & 63;
        float dy = offs[((size_t)b * 18 + 2 * kk)     * HW + ho * W_ + px];
        float dx = offs[((size_t)b * 18 + 2 * kk + 1) * HW + ho * W_ + px];
        float sy = (float)(ho - 1 + kk / 3) + dy;
        float sx = (float)(px - 1 + kk % 3) + dx;
        float y0f = floorf(sy), x0f = floorf(sx);
        float ly = sy - y0f, lx = sx - x0f;
        int y0 = (int)y0f, x0 = (int)x0f;
        int y1 = y0 + 1, x1 = x0 + 1;
        float wy0 = 1.f - ly, wy1 = ly, wx0 = 1.f - lx, wx1 = lx;
        bool vy0 = (y0 >= 0) & (y0 < H_), vy1 = (y1 >= 0) & (y1 < H_);
        bool vx0 = (x0 >= 0) & (x0 < W_), vx1 = (x1 >= 0) & (x1 < W_);
        int cy0 = min(max(y0, 0), H_ - 1), cy1 = min(max(y1, 0), H_ - 1);
        int cx0 = min(max(x0, 0), W_ - 1), cx1 = min(max(x1, 0), W_ - 1);
        int4 ii; float4 ww;
        ii.x = cy0 * W_ + cx0;  ww.x = wy0 * wx0 * ((vy0 & vx0) ? 1.f : 0.f);
        ii.y = cy0 * W_ + cx1;  ww.y = wy0 * wx1 * ((vy0 & vx1) ? 1.f : 0.f);
        ii.z = cy1 * W_ + cx0;  ww.z = wy1 * wx0 * ((vy1 & vx0) ? 1.f : 0.f);
        ii.w = cy1 * W_ + cx1;  ww.w = wy1 * wx1 * ((vy1 & vx1) ? 1.f : 0.f);
        meta_i[e] = ii;
        meta_w[e] = ww;
    }
    __syncthreads();

    const int tx = tid & 15;           // px group: px = tx*4 + 0..3
    const int ty = tid >> 4;           // o group:  o  = ty*16 + 0..15
    float4 acc[16];
#pragma unroll
    for (int j = 0; j < 16; ++j) acc[j] = make_float4(0.f, 0.f, 0.f, 0.f);

    const float* xb_base = x + (size_t)b * C_IN * HW;
    const int px_f = tid & 63;         // for the fill phase
    const int ck0  = tid >> 6;

    for (int chunk = 0; chunk < 32; ++chunk) {
        int c0 = chunk * 8;
        // ---- fill patches p[72][64] for channels c0..c0+7 ----
#pragma unroll
        for (int i = 0; i < 18; ++i) {
            int ck = ck0 + i * 4;              // 0..71
            int k  = ck % 9;
            int cc = ck / 9;
            int m  = k * 64 + px_f;
            int4   ii = meta_i[m];
            float4 ww = meta_w[m];
            const float* xb = xb_base + (size_t)(c0 + cc) * HW;
            p_lds[ck * 64 + px_f] =
                ww.x * xb[ii.x] + ww.y * xb[ii.y] +
                ww.z * xb[ii.z] + ww.w * xb[ii.w];
        }
        __syncthreads();

        // ---- accumulate: 72 ck, 16 o x 4 px per thread ----
        const float* wrow = wT + (size_t)(c0 * 9) * COUT + ty * 16;
#pragma unroll 2
        for (int ck = 0; ck < 72; ++ck) {
            float4 pv = *(const float4*)&p_lds[ck * 64 + tx * 4];
            float4 wa = *(const float4*)(wrow);
            float4 wb = *(const float4*)(wrow + 4);
            float4 wc = *(const float4*)(wrow + 8);
            float4 wd = *(const float4*)(wrow + 12);
            wrow += COUT;
            fma4(acc[0],  wa.x, pv); fma4(acc[1],  wa.y, pv);
            fma4(acc[2],  wa.z, pv); fma4(acc[3],  wa.w, pv);
            fma4(acc[4],  wb.x, pv); fma4(acc[5],  wb.y, pv);
            fma4(acc[6],  wb.z, pv); fma4(acc[7],  wb.w, pv);
            fma4(acc[8],  wc.x, pv); fma4(acc[9],  wc.y, pv);
            fma4(acc[10], wc.z, pv); fma4(acc[11], wc.w, pv);
            fma4(acc[12], wd.x, pv); fma4(acc[13], wd.y, pv);
            fma4(acc[14], wd.z, pv); fma4(acc[15], wd.w, pv);
        }
        __syncthreads();
    }

    // ---- epilogue: write y, reduce sum/sumsq per (b,o) ----
    float* yb = y + (size_t)b * COUT * HW + ho * W_ + tx * 4;
#pragma unroll
    for (int j = 0; j < 16; ++j) {
        int o = ty * 16 + j;
        *(float4*)(yb + (size_t)o * HW) = acc[j];
    }
#pragma unroll
    for (int j = 0; j < 16; ++j) {
        float4 a = acc[j];
        float ls = a.x + a.y + a.z + a.w;
        float lq = a.x * a.x + a.y * a.y + a.z * a.z + a.w * a.w;
#pragma unroll
        for (int m = 8; m >= 1; m >>= 1) {
            ls += __shfl_xor(ls, m, 16);
            lq += __shfl_xor(lq, m, 16);
        }
        if (tx == 0) {
            int o = ty * 16 + j;
            atomicAdd(&sum_[b * COUT + o], ls);
            atomicAdd(&sumsq_[b * COUT + o], lq);
        }
    }
}

// ---------------------------------------------------------------------------
// Kernel C: channel attention (mean + unbiased std -> sigmoid) and scale.
// Grid 2048 (= b*256+o), 256 threads, 4 float4 each.
// ---------------------------------------------------------------------------
__global__ __launch_bounds__(256) void attn_scale_kernel(
    const float* __restrict__ sum_, const float* __restrict__ sumsq_,
    float* __restrict__ y)
{
    int bo = blockIdx.x;
    float s = sum_[bo], q = sumsq_[bo];
    float mean = s * (1.f / 4096.f);
    float var  = (q - s * s * (1.f / 4096.f)) * (1.f / 4095.f);
    float sd   = sqrtf(fmaxf(var, 0.f));
    float attn = 1.f / (1.f + expf(-(mean + sd)));
    float4* yp = (float4*)(y + (size_t)bo * HW);
#pragma unroll
    for (int i = 0; i < 4; ++i) {
        float4 v = yp[threadIdx.x + i * 256];
        v.x *= attn; v.y *= attn; v.z *= attn; v.w *= attn;
        yp[threadIdx.x + i * 256] = v;
    }
}

// ---------------------------------------------------------------------------
extern "C" void kernel_launch(void* const* d_in, const int* in_sizes, int n_in,
                              void* d_out, int out_size, void* d_ws, size_t ws_size,
                              hipStream_t stream)
{
    const float* x  = (const float*)d_in[0];   // [8,256,64,64]
    const float* ow = (const float*)d_in[1];   // [18,256,3,3]
    const float* dw = (const float*)d_in[2];   // [256,256,3,3]
    float* out = (float*)d_out;                // [8,256,64,64]
    float* ws  = (float*)d_ws;

    const size_t OFFN = (size_t)18 * B_ * HW;  // 589824
    float* parts  = ws;                        // 8 * OFFN
    float* offs   = ws + 8 * OFFN;             // OFFN
    float* wT     = ws + 9 * OFFN;             // OFFN (2304*256)
    float* sum_   = ws + 10 * OFFN;            // 2048
    float* sumsq_ = ws + 10 * OFFN + 2048;     // 2048

    hipMemsetAsync(sum_, 0, 2 * 2048 * sizeof(float), stream);

    offset_conv_kernel<<<dim3(128, 8), 256, 0, stream>>>(x, ow, parts);
    offset_reduce_kernel<<<576, 256, 0, stream>>>(parts, offs);
    transpose_w_kernel<<<2304, 256, 0, stream>>>(dw, wT);
    deform_gemm_kernel<<<512, 256, 0, stream>>>(x, offs, wT, out, sum_, sumsq_);
    attn_scale_kernel<<<2048, 256, 0, stream>>>(sum_, sumsq_, out);
}

// Round 2
// 454.877 us; speedup vs baseline: 3.0037x; 3.0037x over previous
//
#include <hip/hip_runtime.h>
#include <hip/hip_bf16.h>
#include <math.h>

#define C_IN 256
#define H_   64
#define W_   64
#define B_   8
#define COUT 256
#define HW   (H_*W_)

typedef float f32x4 __attribute__((ext_vector_type(4)));
typedef short short8 __attribute__((ext_vector_type(8)));

static __device__ __forceinline__ int pack_bf16x2(float a, float b) {
    __hip_bfloat162 h = __float22bfloat162_rn(make_float2(a, b));
    union { __hip_bfloat162 h; int i; } u; u.h = h;
    return u.i;
}

// ---------------------------------------------------------------------------
// Prep: transpose weights to bf16, K-order tap-major.
//   wR[k][o][c]  (9 x 256 x 256 bf16)   from dw[o][c][k]
//   wO[k][o][c]  (9 x  32 x 256 bf16)   from ow[o][c][k], o>=18 zero-padded
// grid 9*288 blocks x 256 thr (tid = c)
// ---------------------------------------------------------------------------
__global__ __launch_bounds__(256) void prep_weights_kernel(
    const float* __restrict__ ow, const float* __restrict__ dw,
    short* __restrict__ wR, short* __restrict__ wO)
{
    int blk = blockIdx.x;
    int k   = blk / 288;
    int row = blk % 288;
    int c   = threadIdx.x;
    union { float f; unsigned u; } a;
    if (row < 256) {
        a.f = dw[(size_t)row * 2304 + c * 9 + k];
        unsigned r = (a.u + 0x7fffu + ((a.u >> 16) & 1u)) >> 16;
        wR[(size_t)k * 65536 + row * 256 + c] = (short)r;
    } else {
        int o = row - 256;                     // 0..31
        a.f = (o < 18) ? ow[(size_t)o * 2304 + c * 9 + k] : 0.f;
        unsigned r = (a.u + 0x7fffu + ((a.u >> 16) & 1u)) >> 16;
        wO[(size_t)k * 8192 + o * 256 + c] = (short)r;
    }
}

// ---------------------------------------------------------------------------
// Offset conv via bf16 MFMA. One block per (b,ho): 64 px x 32 o (o>=18 junk).
// K = 2304 as (tap k)*(256 c); 36 stages of 64 c at fixed tap.
// ---------------------------------------------------------------------------
__global__ __launch_bounds__(256, 2) void offset_mfma_kernel(
    const float* __restrict__ x, const short* __restrict__ wO,
    float* __restrict__ offs)
{
    __shared__ int4 aT[32 * 8];    // [o 32][chunk 8], 16B chunks XOR-swizzled
    __shared__ int4 bT[64 * 8];    // [px 64][chunk 8]

    const int tid = threadIdx.x;
    const int blk = blockIdx.x;
    const int b   = blk >> 6;
    const int ho  = blk & 63;

    const int px = tid & 63;
    const int o8 = tid >> 6;           // 0..3
    const int wv = tid >> 6;           // wave id
    const int ln = tid & 63;
    const int lo = ln & 15;
    const int quad = ln >> 4;

    f32x4 acc[2];
    acc[0] = (f32x4){0.f, 0.f, 0.f, 0.f};
    acc[1] = (f32x4){0.f, 0.f, 0.f, 0.f};

    const float* xbb = x + ((size_t)b << 20);
    const int oA = tid >> 3;           // 0..31  (A staging)
    const int octA = tid & 7;

    for (int s = 0; s < 36; ++s) {
        int k  = s >> 2;
        int c0 = (s & 3) << 6;
        int dy = k / 3 - 1, dx = k % 3 - 1;
        int yy = ho + dy;
        int xx = px + dx;
        bool valid = (yy >= 0) & (yy < 64) & (xx >= 0) & (xx < 64);
        float msk = valid ? 1.f : 0.f;
        int yc = min(max(yy, 0), 63), xc = min(max(xx, 0), 63);
        int idx = yc * 64 + xc;

        // ---- gather B tile: shifted x, bf16, swizzled ----
#pragma unroll
        for (int t = 0; t < 2; ++t) {
            int oct = o8 + t * 4;
            int cbase = (c0 + oct * 8) << 12;   // *HW
            float v[8];
#pragma unroll
            for (int j = 0; j < 8; ++j)
                v[j] = msk * xbb[cbase + (j << 12) + idx];
            int4 pk;
            pk.x = pack_bf16x2(v[0], v[1]);
            pk.y = pack_bf16x2(v[2], v[3]);
            pk.z = pack_bf16x2(v[4], v[5]);
            pk.w = pack_bf16x2(v[6], v[7]);
            bT[px * 8 + (oct ^ (px & 7))] = pk;
        }
        // ---- stage A tile (4 KB) ----
        aT[oA * 8 + (octA ^ (oA & 7))] =
            *(const int4*)(wO + (size_t)k * 8192 + oA * 256 + c0 + octA * 8);
        __syncthreads();

        // ---- MFMA: wave wv owns px-tile wv (16 px) x 32 o ----
        int pxl = wv * 16 + lo;
#pragma unroll
        for (int ks = 0; ks < 2; ++ks) {
            int ch = ks * 4 + quad;
            short8 bfr = *(const short8*)&bT[pxl * 8 + (ch ^ (pxl & 7))];
#pragma unroll
            for (int t = 0; t < 2; ++t) {
                int o = t * 16 + lo;
                short8 afr = *(const short8*)&aT[o * 8 + (ch ^ (o & 7))];
                acc[t] = __builtin_amdgcn_mfma_f32_16x16x32_bf16(afr, bfr, acc[t], 0, 0, 0);
            }
        }
        __syncthreads();
    }

    // ---- epilogue: write offsets (o<18), fp32 ----
#pragma unroll
    for (int t = 0; t < 2; ++t) {
#pragma unroll
        for (int r = 0; r < 4; ++r) {
            int o = t * 16 + quad * 4 + r;
            if (o < 18)
                offs[((size_t)b * 18 + o) * HW + ho * 64 + wv * 16 + lo] = acc[t][r];
        }
    }
}

// ---------------------------------------------------------------------------
// Deformable conv via bf16 MFMA. One block per (b,ho): 64 px x 256 o.
// K = (tap)*(c); stage = fixed tap, 64 channels. Bilinear gather -> LDS bf16.
// Wave wv computes o in [wv*64, wv*64+64) x all 64 px.
// ---------------------------------------------------------------------------
__global__ __launch_bounds__(256, 2) void deform_mfma_kernel(
    const float* __restrict__ x, const float* __restrict__ offs,
    const short* __restrict__ wR, float* __restrict__ y,
    float* __restrict__ sum_, float* __restrict__ sumsq_)
{
    __shared__ int4   meta_i[576];   // [k][px] corner indices (elem idx in HW)
    __shared__ float4 meta_w[576];   // [k][px] corner weights
    __shared__ int4   aT[256 * 8];   // [o 256][chunk 8] bf16 weights, swizzled
    __shared__ int4   bT[64 * 8];    // [px 64][chunk 8] bf16 patches, swizzled

    const int tid = threadIdx.x;
    const int blk = blockIdx.x;
    const int b   = blk >> 6;
    const int ho  = blk & 63;

    // ---- meta phase: bilinear indices + weights for 64 px x 9 taps ----
    for (int e = tid; e < 576; e += 256) {
        int kk = e >> 6;
        int pxe = e & 63;
        float dy = offs[((size_t)b * 18 + 2 * kk)     * HW + ho * W_ + pxe];
        float dx = offs[((size_t)b * 18 + 2 * kk + 1) * HW + ho * W_ + pxe];
        float sy = (float)(ho - 1 + kk / 3) + dy;
        float sx = (float)(pxe - 1 + kk % 3) + dx;
        float y0f = floorf(sy), x0f = floorf(sx);
        float ly = sy - y0f, lx = sx - x0f;
        int y0 = (int)y0f, x0 = (int)x0f;
        int y1 = y0 + 1, x1 = x0 + 1;
        float wy0 = 1.f - ly, wy1 = ly, wx0 = 1.f - lx, wx1 = lx;
        bool vy0 = (y0 >= 0) & (y0 < H_), vy1 = (y1 >= 0) & (y1 < H_);
        bool vx0 = (x0 >= 0) & (x0 < W_), vx1 = (x1 >= 0) & (x1 < W_);
        int cy0 = min(max(y0, 0), H_ - 1), cy1 = min(max(y1, 0), H_ - 1);
        int cx0 = min(max(x0, 0), W_ - 1), cx1 = min(max(x1, 0), W_ - 1);
        int4 ii; float4 ww;
        ii.x = cy0 * W_ + cx0;  ww.x = wy0 * wx0 * ((vy0 & vx0) ? 1.f : 0.f);
        ii.y = cy0 * W_ + cx1;  ww.y = wy0 * wx1 * ((vy0 & vx1) ? 1.f : 0.f);
        ii.z = cy1 * W_ + cx0;  ww.z = wy1 * wx0 * ((vy1 & vx0) ? 1.f : 0.f);
        ii.w = cy1 * W_ + cx1;  ww.w = wy1 * wx1 * ((vy1 & vx1) ? 1.f : 0.f);
        meta_i[e] = ii;
        meta_w[e] = ww;
    }

    const int px = tid & 63;
    const int o8 = tid >> 6;
    const int wv = tid >> 6;
    const int ln = tid & 63;
    const int lo = ln & 15;
    const int quad = ln >> 4;

    f32x4 acc[4][4];
#pragma unroll
    for (int t = 0; t < 4; ++t)
#pragma unroll
        for (int p = 0; p < 4; ++p)
            acc[t][p] = (f32x4){0.f, 0.f, 0.f, 0.f};

    const float* xbb = x + ((size_t)b << 20);
    const int oA = tid >> 3;           // 0..31 (+32/iter)
    const int octA = tid & 7;

    __syncthreads();

    for (int s = 0; s < 36; ++s) {
        int k  = s >> 2;
        int c0 = (s & 3) << 6;

        int4   ii = meta_i[k * 64 + px];
        float4 ww = meta_w[k * 64 + px];

        // ---- gather B tile: bilinear sample 16 channels/thread ----
#pragma unroll
        for (int t = 0; t < 2; ++t) {
            int oct = o8 + t * 4;
            int cbase = (c0 + oct * 8) << 12;
            float v[8];
#pragma unroll
            for (int j = 0; j < 8; ++j) {
                int cb = cbase + (j << 12);
                v[j] = ww.x * xbb[cb + ii.x] + ww.y * xbb[cb + ii.y]
                     + ww.z * xbb[cb + ii.z] + ww.w * xbb[cb + ii.w];
            }
            int4 pk;
            pk.x = pack_bf16x2(v[0], v[1]);
            pk.y = pack_bf16x2(v[2], v[3]);
            pk.z = pack_bf16x2(v[4], v[5]);
            pk.w = pack_bf16x2(v[6], v[7]);
            bT[px * 8 + (oct ^ (px & 7))] = pk;
        }

        // ---- stage A tile (32 KB): wR[k][o][c0..c0+63] ----
        const short* wk = wR + (size_t)k * 65536 + c0;
#pragma unroll
        for (int it = 0; it < 8; ++it) {
            int o = oA + it * 32;
            aT[o * 8 + (octA ^ (o & 7))] = *(const int4*)(wk + o * 256 + octA * 8);
        }
        __syncthreads();

        // ---- MFMA: 2 k-steps x 4 o-tiles x 4 px-tiles ----
#pragma unroll
        for (int ks = 0; ks < 2; ++ks) {
            int ch = ks * 4 + quad;
            short8 afr[4], bfr[4];
#pragma unroll
            for (int t = 0; t < 4; ++t) {
                int o = wv * 64 + t * 16 + lo;
                afr[t] = *(const short8*)&aT[o * 8 + (ch ^ (o & 7))];
                int p = t * 16 + lo;
                bfr[t] = *(const short8*)&bT[p * 8 + (ch ^ (p & 7))];
            }
#pragma unroll
            for (int t = 0; t < 4; ++t)
#pragma unroll
                for (int p = 0; p < 4; ++p)
                    acc[t][p] = __builtin_amdgcn_mfma_f32_16x16x32_bf16(
                        afr[t], bfr[p], acc[t][p], 0, 0, 0);
        }
        __syncthreads();
    }

    // ---- epilogue: store y + per-(b,o) sum/sumsq atomics ----
    float* yb = y + ((size_t)b << 20) + ho * 64;
#pragma unroll
    for (int t = 0; t < 4; ++t) {
#pragma unroll
        for (int r = 0; r < 4; ++r) {
            int o = wv * 64 + t * 16 + quad * 4 + r;
            float sv = 0.f, qv = 0.f;
#pragma unroll
            for (int p = 0; p < 4; ++p) {
                float val = acc[t][p][r];
                yb[(size_t)o * HW + p * 16 + lo] = val;
                sv += val;
                qv += val * val;
            }
#pragma unroll
            for (int m = 1; m <= 8; m <<= 1) {
                sv += __shfl_xor(sv, m, 16);
                qv += __shfl_xor(qv, m, 16);
            }
            if (lo == 0) {
                atomicAdd(&sum_[b * COUT + o], sv);
                atomicAdd(&sumsq_[b * COUT + o], qv);
            }
        }
    }
}

// ---------------------------------------------------------------------------
// Channel attention (mean + unbiased std -> sigmoid) and scale.
// ---------------------------------------------------------------------------
__global__ __launch_bounds__(256) void attn_scale_kernel(
    const float* __restrict__ sum_, const float* __restrict__ sumsq_,
    float* __restrict__ y)
{
    int bo = blockIdx.x;
    float s = sum_[bo], q = sumsq_[bo];
    float mean = s * (1.f / 4096.f);
    float var  = (q - s * s * (1.f / 4096.f)) * (1.f / 4095.f);
    float sd   = sqrtf(fmaxf(var, 0.f));
    float attn = 1.f / (1.f + expf(-(mean + sd)));
    float4* yp = (float4*)(y + (size_t)bo * HW);
#pragma unroll
    for (int i = 0; i < 4; ++i) {
        float4 v = yp[threadIdx.x + i * 256];
        v.x *= attn; v.y *= attn; v.z *= attn; v.w *= attn;
        yp[threadIdx.x + i * 256] = v;
    }
}

// ---------------------------------------------------------------------------
extern "C" void kernel_launch(void* const* d_in, const int* in_sizes, int n_in,
                              void* d_out, int out_size, void* d_ws, size_t ws_size,
                              hipStream_t stream)
{
    const float* x  = (const float*)d_in[0];   // [8,256,64,64]
    const float* ow = (const float*)d_in[1];   // [18,256,3,3]
    const float* dw = (const float*)d_in[2];   // [256,256,3,3]
    float* out = (float*)d_out;                // [8,256,64,64]
    float* ws  = (float*)d_ws;

    float* offs   = ws;                        // 589824 floats
    short* wR     = (short*)(ws + 589824);     // 589824 bf16
    short* wO     = wR + 589824;               // 73728 bf16
    float* sum_   = (float*)(wO + 73728);      // 2048
    float* sumsq_ = sum_ + 2048;               // 2048

    hipMemsetAsync(sum_, 0, 2 * 2048 * sizeof(float), stream);

    prep_weights_kernel<<<9 * 288, 256, 0, stream>>>(ow, dw, wR, wO);
    offset_mfma_kernel<<<512, 256, 0, stream>>>(x, wO, offs);
    deform_mfma_kernel<<<512, 256, 0, stream>>>(x, offs, wR, out, sum_, sumsq_);
    attn_scale_kernel<<<2048, 256, 0, stream>>>(sum_, sumsq_, out);
}

// Round 3
// 198.178 us; speedup vs baseline: 6.8945x; 2.2953x over previous
//
#include <hip/hip_runtime.h>
#include <hip/hip_bf16.h>
#include <math.h>

#define C_IN 256
#define H_   64
#define W_   64
#define B_   8
#define COUT 256
#define HW   (H_*W_)

typedef float f32x4 __attribute__((ext_vector_type(4)));
typedef short short8 __attribute__((ext_vector_type(8)));

static __device__ __forceinline__ int pack_bf16x2(float a, float b) {
    __hip_bfloat162 h = __float22bfloat162_rn(make_float2(a, b));
    union { __hip_bfloat162 h; int i; } u; u.h = h;
    return u.i;
}

static __device__ __forceinline__ void unpk(int v, float& lo, float& hi) {
    union { int i; float f; } a, b;
    a.i = v << 16;
    b.i = v & 0xffff0000;
    lo = a.f; hi = b.f;
}

// ---------------------------------------------------------------------------
// Prep: weights -> bf16, K-order tap-major.
//   wR[k][o][c] (9 x 256 x 256), wO[k][o][c] (9 x 32 x 256, o>=18 zero)
// ---------------------------------------------------------------------------
__global__ __launch_bounds__(256) void prep_weights_kernel(
    const float* __restrict__ ow, const float* __restrict__ dw,
    short* __restrict__ wR, short* __restrict__ wO)
{
    int blk = blockIdx.x;
    int k   = blk / 288;
    int row = blk % 288;
    int c   = threadIdx.x;
    union { float f; unsigned u; } a;
    if (row < 256) {
        a.f = dw[(size_t)row * 2304 + c * 9 + k];
        unsigned r = (a.u + 0x7fffu + ((a.u >> 16) & 1u)) >> 16;
        wR[(size_t)k * 65536 + row * 256 + c] = (short)r;
    } else {
        int o = row - 256;
        a.f = (o < 18) ? ow[(size_t)o * 2304 + c * 9 + k] : 0.f;
        unsigned r = (a.u + 0x7fffu + ((a.u >> 16) & 1u)) >> 16;
        wO[(size_t)k * 8192 + o * 256 + c] = (short)r;
    }
}

// ---------------------------------------------------------------------------
// Transpose x: NCHW fp32 -> NHWC bf16  xT[b][h][w][c]. One block per (b,h).
// ---------------------------------------------------------------------------
__global__ __launch_bounds__(256) void transpose_x_kernel(
    const float* __restrict__ x, unsigned short* __restrict__ xT)
{
    __shared__ float tile[64][257];        // [w][c], pad -> conflict-free writes
    const int tid = threadIdx.x;
    const int b = blockIdx.x >> 6, h = blockIdx.x & 63;
    const float* xb = x + ((size_t)b << 20) + h * 64;

#pragma unroll
    for (int pass = 0; pass < 16; ++pass) {
        int c  = pass * 16 + (tid >> 4);
        int w0 = (tid & 15) * 4;
        float4 v = *(const float4*)(xb + (size_t)c * 4096 + w0);
        tile[w0][c] = v.x; tile[w0 + 1][c] = v.y;
        tile[w0 + 2][c] = v.z; tile[w0 + 3][c] = v.w;
    }
    __syncthreads();

    int4* ob = (int4*)(xT + ((size_t)blockIdx.x << 14));   // 64*256 shorts
#pragma unroll
    for (int pass = 0; pass < 8; ++pass) {
        int idx = pass * 256 + tid;        // 0..2047
        int w = idx >> 5, ch8 = idx & 31;
        const float* tr = &tile[w][ch8 * 8];
        int4 pk;
        pk.x = pack_bf16x2(tr[0], tr[1]);
        pk.y = pack_bf16x2(tr[2], tr[3]);
        pk.z = pack_bf16x2(tr[4], tr[5]);
        pk.w = pack_bf16x2(tr[6], tr[7]);
        ob[idx] = pk;
    }
}

// ---------------------------------------------------------------------------
// Offset conv via bf16 MFMA, NHWC input. One block per (b,ho), b = blk&7
// (XCD-pinned). 64 px x 32 o, K = tap*ch, 36 stages of (tap, 64 ch).
// ---------------------------------------------------------------------------
__global__ __launch_bounds__(256, 2) void offset_mfma_kernel(
    const unsigned short* __restrict__ xT, const short* __restrict__ wO,
    float* __restrict__ offs)
{
    __shared__ int4 aT[32 * 8];
    __shared__ int4 bT[64 * 8];

    const int tid = threadIdx.x;
    const int b   = blockIdx.x & 7;        // XCD pin
    const int ho  = blockIdx.x >> 3;

    const int px = tid >> 2;               // 0..63
    const int cg = tid & 3;                // 16-ch group
    const int wv = tid >> 6;
    const int ln = tid & 63;
    const int lo = ln & 15;
    const int quad = ln >> 4;

    f32x4 acc[2];
    acc[0] = (f32x4){0.f, 0.f, 0.f, 0.f};
    acc[1] = (f32x4){0.f, 0.f, 0.f, 0.f};

    const unsigned short* xbb = xT + ((size_t)b << 20);
    const int oA = tid >> 3, octA = tid & 7;
    const int4 zero4 = {0, 0, 0, 0};

    for (int s = 0; s < 36; ++s) {
        int k  = s >> 2;
        int c0 = (s & 3) << 6;
        int yy = ho + k / 3 - 1;
        int xx = px + k % 3 - 1;
        bool valid = (yy >= 0) & (yy < 64) & (xx >= 0) & (xx < 64);
        int yc = min(max(yy, 0), 63), xc = min(max(xx, 0), 63);

        const int4* src = (const int4*)(xbb + (((size_t)yc * 64 + xc) << 8) + c0 + cg * 16);
        int4 p0 = valid ? src[0] : zero4;
        int4 p1 = valid ? src[1] : zero4;
        bT[px * 8 + ((2 * cg)     ^ (px & 7))] = p0;
        bT[px * 8 + ((2 * cg + 1) ^ (px & 7))] = p1;

        aT[oA * 8 + (octA ^ (oA & 7))] =
            *(const int4*)(wO + (size_t)k * 8192 + oA * 256 + c0 + octA * 8);
        __syncthreads();

        int pxl = wv * 16 + lo;
#pragma unroll
        for (int ks = 0; ks < 2; ++ks) {
            int ch = ks * 4 + quad;
            short8 bfr = *(const short8*)&bT[pxl * 8 + (ch ^ (pxl & 7))];
#pragma unroll
            for (int t = 0; t < 2; ++t) {
                int o = t * 16 + lo;
                short8 afr = *(const short8*)&aT[o * 8 + (ch ^ (o & 7))];
                acc[t] = __builtin_amdgcn_mfma_f32_16x16x32_bf16(afr, bfr, acc[t], 0, 0, 0);
            }
        }
        __syncthreads();
    }

#pragma unroll
    for (int t = 0; t < 2; ++t) {
#pragma unroll
        for (int r = 0; r < 4; ++r) {
            int o = t * 16 + quad * 4 + r;
            if (o < 18)
                offs[((size_t)b * 18 + o) * HW + ho * 64 + wv * 16 + lo] = acc[t][r];
        }
    }
}

// ---------------------------------------------------------------------------
// Deformable conv via bf16 MFMA, NHWC input. One block per (b,ho), b = blk&7.
// 64 px x 256 o. Stage = (tap, 64 ch): bilinear gather (fp32 blend of bf16
// corners, contiguous-channel dwordx4 loads) -> LDS -> MFMA.
// ---------------------------------------------------------------------------
__global__ __launch_bounds__(256, 2) void deform_mfma_kernel(
    const unsigned short* __restrict__ xT, const float* __restrict__ offs,
    const short* __restrict__ wR, float* __restrict__ y,
    float* __restrict__ sum_, float* __restrict__ sumsq_)
{
    __shared__ int4   meta_i[576];
    __shared__ float4 meta_w[576];
    __shared__ int4   aT[256 * 8];
    __shared__ int4   bT[64 * 8];

    const int tid = threadIdx.x;
    const int b   = blockIdx.x & 7;        // XCD pin
    const int ho  = blockIdx.x >> 3;

    for (int e = tid; e < 576; e += 256) {
        int kk = e >> 6;
        int pxe = e & 63;
        float dy = offs[((size_t)b * 18 + 2 * kk)     * HW + ho * W_ + pxe];
        float dx = offs[((size_t)b * 18 + 2 * kk + 1) * HW + ho * W_ + pxe];
        float sy = (float)(ho - 1 + kk / 3) + dy;
        float sx = (float)(pxe - 1 + kk % 3) + dx;
        float y0f = floorf(sy), x0f = floorf(sx);
        float ly = sy - y0f, lx = sx - x0f;
        int y0 = (int)y0f, x0 = (int)x0f;
        int y1 = y0 + 1, x1 = x0 + 1;
        float wy0 = 1.f - ly, wy1 = ly, wx0 = 1.f - lx, wx1 = lx;
        bool vy0 = (y0 >= 0) & (y0 < H_), vy1 = (y1 >= 0) & (y1 < H_);
        bool vx0 = (x0 >= 0) & (x0 < W_), vx1 = (x1 >= 0) & (x1 < W_);
        int cy0 = min(max(y0, 0), H_ - 1), cy1 = min(max(y1, 0), H_ - 1);
        int cx0 = min(max(x0, 0), W_ - 1), cx1 = min(max(x1, 0), W_ - 1);
        int4 ii; float4 ww;
        ii.x = cy0 * W_ + cx0;  ww.x = wy0 * wx0 * ((vy0 & vx0) ? 1.f : 0.f);
        ii.y = cy0 * W_ + cx1;  ww.y = wy0 * wx1 * ((vy0 & vx1) ? 1.f : 0.f);
        ii.z = cy1 * W_ + cx0;  ww.z = wy1 * wx0 * ((vy1 & vx0) ? 1.f : 0.f);
        ii.w = cy1 * W_ + cx1;  ww.w = wy1 * wx1 * ((vy1 & vx1) ? 1.f : 0.f);
        meta_i[e] = ii;
        meta_w[e] = ww;
    }

    const int px = tid >> 2;
    const int cg = tid & 3;
    const int wv = tid >> 6;
    const int ln = tid & 63;
    const int lo = ln & 15;
    const int quad = ln >> 4;

    f32x4 acc[4][4];
#pragma unroll
    for (int t = 0; t < 4; ++t)
#pragma unroll
        for (int p = 0; p < 4; ++p)
            acc[t][p] = (f32x4){0.f, 0.f, 0.f, 0.f};

    const unsigned short* xbb = xT + ((size_t)b << 20) + cg * 16;
    const int oA = tid >> 3, octA = tid & 7;

    __syncthreads();

    for (int s = 0; s < 36; ++s) {
        int k  = s >> 2;
        int c0 = (s & 3) << 6;

        int4   ii = meta_i[k * 64 + px];
        float4 ww = meta_w[k * 64 + px];

        const unsigned short* xc0 = xbb + c0;
        const int4* pA = (const int4*)(xc0 + ((size_t)ii.x << 8));
        const int4* pB = (const int4*)(xc0 + ((size_t)ii.y << 8));
        const int4* pC = (const int4*)(xc0 + ((size_t)ii.z << 8));
        const int4* pD = (const int4*)(xc0 + ((size_t)ii.w << 8));
        int4 a0 = pA[0], a1 = pA[1];
        int4 b0 = pB[0], b1 = pB[1];
        int4 cc0 = pC[0], cc1 = pC[1];
        int4 d0 = pD[0], d1 = pD[1];

        auto blend = [&](int av, int bv, int cv, int dv) -> int {
            float alo, ahi, blo, bhi, clo, chi, dlo, dhi;
            unpk(av, alo, ahi); unpk(bv, blo, bhi);
            unpk(cv, clo, chi); unpk(dv, dlo, dhi);
            float vlo = ww.x * alo + ww.y * blo + ww.z * clo + ww.w * dlo;
            float vhi = ww.x * ahi + ww.y * bhi + ww.z * chi + ww.w * dhi;
            return pack_bf16x2(vlo, vhi);
        };
        int4 o0, o1;
        o0.x = blend(a0.x, b0.x, cc0.x, d0.x);
        o0.y = blend(a0.y, b0.y, cc0.y, d0.y);
        o0.z = blend(a0.z, b0.z, cc0.z, d0.z);
        o0.w = blend(a0.w, b0.w, cc0.w, d0.w);
        o1.x = blend(a1.x, b1.x, cc1.x, d1.x);
        o1.y = blend(a1.y, b1.y, cc1.y, d1.y);
        o1.z = blend(a1.z, b1.z, cc1.z, d1.z);
        o1.w = blend(a1.w, b1.w, cc1.w, d1.w);
        bT[px * 8 + ((2 * cg)     ^ (px & 7))] = o0;
        bT[px * 8 + ((2 * cg + 1) ^ (px & 7))] = o1;

        const short* wk = wR + (size_t)k * 65536 + c0;
#pragma unroll
        for (int it = 0; it < 8; ++it) {
            int o = oA + it * 32;
            aT[o * 8 + (octA ^ (o & 7))] = *(const int4*)(wk + o * 256 + octA * 8);
        }
        __syncthreads();

#pragma unroll
        for (int ks = 0; ks < 2; ++ks) {
            int ch = ks * 4 + quad;
            short8 afr[4], bfr[4];
#pragma unroll
            for (int t = 0; t < 4; ++t) {
                int o = wv * 64 + t * 16 + lo;
                afr[t] = *(const short8*)&aT[o * 8 + (ch ^ (o & 7))];
                int p = t * 16 + lo;
                bfr[t] = *(const short8*)&bT[p * 8 + (ch ^ (p & 7))];
            }
#pragma unroll
            for (int t = 0; t < 4; ++t)
#pragma unroll
                for (int p = 0; p < 4; ++p)
                    acc[t][p] = __builtin_amdgcn_mfma_f32_16x16x32_bf16(
                        afr[t], bfr[p], acc[t][p], 0, 0, 0);
        }
        __syncthreads();
    }

    float* yb = y + ((size_t)b << 20) + ho * 64;
#pragma unroll
    for (int t = 0; t < 4; ++t) {
#pragma unroll
        for (int r = 0; r < 4; ++r) {
            int o = wv * 64 + t * 16 + quad * 4 + r;
            float sv = 0.f, qv = 0.f;
#pragma unroll
            for (int p = 0; p < 4; ++p) {
                float val = acc[t][p][r];
                yb[(size_t)o * HW + p * 16 + lo] = val;
                sv += val;
                qv += val * val;
            }
#pragma unroll
            for (int m = 1; m <= 8; m <<= 1) {
                sv += __shfl_xor(sv, m, 16);
                qv += __shfl_xor(qv, m, 16);
            }
            if (lo == 0) {
                atomicAdd(&sum_[b * COUT + o], sv);
                atomicAdd(&sumsq_[b * COUT + o], qv);
            }
        }
    }
}

// ---------------------------------------------------------------------------
// Channel attention (mean + unbiased std -> sigmoid) and scale.
// ---------------------------------------------------------------------------
__global__ __launch_bounds__(256) void attn_scale_kernel(
    const float* __restrict__ sum_, const float* __restrict__ sumsq_,
    float* __restrict__ y)
{
    int bo = blockIdx.x;
    float s = sum_[bo], q = sumsq_[bo];
    float mean = s * (1.f / 4096.f);
    float var  = (q - s * s * (1.f / 4096.f)) * (1.f / 4095.f);
    float sd   = sqrtf(fmaxf(var, 0.f));
    float attn = 1.f / (1.f + expf(-(mean + sd)));
    float4* yp = (float4*)(y + (size_t)bo * HW);
#pragma unroll
    for (int i = 0; i < 4; ++i) {
        float4 v = yp[threadIdx.x + i * 256];
        v.x *= attn; v.y *= attn; v.z *= attn; v.w *= attn;
        yp[threadIdx.x + i * 256] = v;
    }
}

// ---------------------------------------------------------------------------
extern "C" void kernel_launch(void* const* d_in, const int* in_sizes, int n_in,
                              void* d_out, int out_size, void* d_ws, size_t ws_size,
                              hipStream_t stream)
{
    const float* x  = (const float*)d_in[0];   // [8,256,64,64]
    const float* ow = (const float*)d_in[1];   // [18,256,3,3]
    const float* dw = (const float*)d_in[2];   // [256,256,3,3]
    float* out = (float*)d_out;                // [8,256,64,64]
    float* ws  = (float*)d_ws;

    float*          offs = ws;                              // 589824 f
    unsigned short* xT   = (unsigned short*)(ws + 589824);  // 8388608 us
    short*          wR   = (short*)(xT + 8388608);          // 589824
    short*          wO   = wR + 589824;                     // 73728
    float*          sum_ = (float*)(wO + 73728);            // 2048
    float*          sumsq_ = sum_ + 2048;                   // 2048

    hipMemsetAsync(sum_, 0, 2 * 2048 * sizeof(float), stream);

    prep_weights_kernel<<<9 * 288, 256, 0, stream>>>(ow, dw, wR, wO);
    transpose_x_kernel<<<512, 256, 0, stream>>>(x, xT);
    offset_mfma_kernel<<<512, 256, 0, stream>>>(xT, wO, offs);
    deform_mfma_kernel<<<512, 256, 0, stream>>>(xT, offs, wR, out, sum_, sumsq_);
    attn_scale_kernel<<<2048, 256, 0, stream>>>(sum_, sumsq_, out);
}